// Round 2
// baseline (411.633 us; speedup 1.0000x reference)
//
#include <hip/hip_runtime.h>
#include <cstdint>

typedef unsigned short u16;
typedef unsigned int u32;
typedef __attribute__((ext_vector_type(8))) short short8;
typedef __attribute__((ext_vector_type(4))) float f32x4;

static constexpr int Bc = 2, Sc = 2048, DMc = 1024, Hc = 16, DKc = 64;
static constexpr int Mc = Bc * Sc; // 4096

__device__ __forceinline__ float b2f(u16 u) { return __uint_as_float((u32)u << 16); }
__device__ __forceinline__ u16 f2b(float f) {
  u32 x = __float_as_uint(f);
  return (u16)((x + 0x7fffu + ((x >> 16) & 1u)) >> 16);
}
__device__ __forceinline__ u32 pack2(float lo, float hi) {
  return (u32)f2b(lo) | ((u32)f2b(hi) << 16);
}

// ---------------- f32 -> bf16 conversion (RTNE), 8 elems/thread ---------------
__global__ __launch_bounds__(256)
void cvt_f32_bf16_k(const float* __restrict__ src, u16* __restrict__ dst, int n8)
{
  const int i = blockIdx.x * 256 + threadIdx.x;
  if (i >= n8) return;
  const float4 a = *(const float4*)(src + (size_t)i * 8);
  const float4 b = *(const float4*)(src + (size_t)i * 8 + 4);
  uint4 o;
  o.x = pack2(a.x, a.y);
  o.y = pack2(a.z, a.w);
  o.z = pack2(b.x, b.y);
  o.w = pack2(b.z, b.w);
  *(uint4*)(dst + (size_t)i * 8) = o;
}

// ---------------- GEMM: C[M][N] = A[M][K] * W[N][K]^T, bf16 in, f32 acc -------
// m97 structure: 128x128 tile, BK=32, 4 waves (2x2), global_load_lds width 16.
template <typename OutT>
__global__ __launch_bounds__(256, 2)
void gemm_bt128(const u16* __restrict__ A, const u16* __restrict__ W,
                OutT* __restrict__ C, int M, int N, int K)
{
  __shared__ u16 As[128 * 32];
  __shared__ u16 Bs[128 * 32];
  const int t = threadIdx.x;
  const int w = t >> 6, l = t & 63;
  const int wr = w >> 1, wc = w & 1;
  const int l4 = l >> 4, l15 = l & 15;
  const int bm = blockIdx.x, bn = blockIdx.y;

  f32x4 acc[4][4] = {};

  const int rowA = bm * 128, rowB = bn * 128;
  const int sr = l >> 2, sk = (l & 3) * 8; // staging: lane -> (row, k) within 16x32 chunk

  for (int k0 = 0; k0 < K; k0 += 32) {
    __syncthreads();
#pragma unroll
    for (int i = 0; i < 2; ++i) {
      const int chunk = i * 4 + w; // 8 chunks of 16 rows x 32 k
      const u16* ga = A + (size_t)(rowA + chunk * 16 + sr) * K + k0 + sk;
      const u16* gb = W + (size_t)(rowB + chunk * 16 + sr) * K + k0 + sk;
      __builtin_amdgcn_global_load_lds((const __attribute__((address_space(1))) void*)ga,
                                       (__attribute__((address_space(3))) void*)(As + chunk * 512), 16, 0, 0);
      __builtin_amdgcn_global_load_lds((const __attribute__((address_space(1))) void*)gb,
                                       (__attribute__((address_space(3))) void*)(Bs + chunk * 512), 16, 0, 0);
    }
    __syncthreads();
    short8 af[4], bf[4];
#pragma unroll
    for (int m = 0; m < 4; ++m)
      af[m] = *(const short8*)(As + (wr * 64 + m * 16 + l15) * 32 + l4 * 8);
#pragma unroll
    for (int n = 0; n < 4; ++n)
      bf[n] = *(const short8*)(Bs + (wc * 64 + n * 16 + l15) * 32 + l4 * 8);
#pragma unroll
    for (int m = 0; m < 4; ++m)
#pragma unroll
      for (int n = 0; n < 4; ++n)
        acc[m][n] = __builtin_amdgcn_mfma_f32_16x16x32_bf16(af[m], bf[n], acc[m][n], 0, 0, 0);
  }

#pragma unroll
  for (int m = 0; m < 4; ++m) {
    const int r0 = rowA + wr * 64 + m * 16 + l4 * 4;
#pragma unroll
    for (int n = 0; n < 4; ++n) {
      const int c0 = rowB + wc * 64 + n * 16 + l15;
#pragma unroll
      for (int r = 0; r < 4; ++r) {
        const float v = acc[m][n][r];
        if constexpr (sizeof(OutT) == 2)
          C[(size_t)(r0 + r) * N + c0] = (OutT)f2b(v);
        else
          C[(size_t)(r0 + r) * N + c0] = (OutT)v;
      }
    }
  }
}

// ---------------- RoPE cos/sin table: [S][32] float2 --------------------------
__global__ void rope_table_k(float2* __restrict__ tab)
{
  const int idx = blockIdx.x * 256 + threadIdx.x; // S*32 total
  const int p = idx >> 5, i = idx & 31;
  const float invf = powf(10000.0f, -(float)(2 * i) / 64.0f);
  const float ang = (float)p * invf;
  tab[idx] = make_float2(cosf(ang), sinf(ang));
}

// ---------------- RoPE apply + relayout ---------------------------------------
// qkv ws [B*S][3*1024] -> Q[B,H,S,64] (rope, *0.125), K[B,H,S,64] (rope),
// Vt[B,H,64,S] (transposed for PV B-fragments).
__global__ __launch_bounds__(256)
void rope_reshape_k(const u16* __restrict__ qkv, const int* __restrict__ tokpos,
                    const float2* __restrict__ tab,
                    u16* __restrict__ Q, u16* __restrict__ K, u16* __restrict__ Vt)
{
  __shared__ u16 Vs[64][72]; // +8 pad keeps 16B alignment, breaks bank conflicts
  const int t = threadIdx.x;
  const int st = blockIdx.x, h = blockIdx.y, b = blockIdx.z;

  {
    const int sl = t >> 2, iq = t & 3; // 4 threads cover one s-row's 64 dims
    const int s = st * 64 + sl;
    const int p = tokpos[b * Sc + s];
    const size_t row = (size_t)(b * Sc + s) * 3 * DMc + h * DKc + iq * 16;
    const size_t orow = ((size_t)(b * Hc + h) * Sc + s) * DKc + iq * 16;
#pragma unroll
    for (int which = 0; which < 2; ++which) {
      const u16* g = qkv + row + which * DMc;
      uint4 va = *(const uint4*)g;
      uint4 vb = *(const uint4*)(g + 8);
      u32 in[8] = {va.x, va.y, va.z, va.w, vb.x, vb.y, vb.z, vb.w};
      const float scale = (which == 0) ? 0.125f : 1.0f; // fold 1/sqrt(64) into Q
      u32 ow[8];
#pragma unroll
      for (int j = 0; j < 8; ++j) {
        const float2 cs = tab[p * 32 + iq * 8 + j];
        const float t1 = b2f((u16)(in[j] & 0xffffu));
        const float t2 = b2f((u16)(in[j] >> 16));
        ow[j] = pack2((t1 * cs.x - t2 * cs.y) * scale, (t1 * cs.y + t2 * cs.x) * scale);
      }
      u16* dst = (which == 0 ? Q : K) + orow;
      *(uint4*)dst = make_uint4(ow[0], ow[1], ow[2], ow[3]);
      *(uint4*)(dst + 8) = make_uint4(ow[4], ow[5], ow[6], ow[7]);
    }
  }
  // V transpose via LDS
#pragma unroll
  for (int it = 0; it < 2; ++it) {
    const int sv = it * 32 + (t >> 3);
    const int d0 = (t & 7) * 8;
    const u16* g = qkv + (size_t)(b * Sc + st * 64 + sv) * 3 * DMc + 2 * DMc + h * DKc + d0;
    *(uint4*)&Vs[sv][d0] = *(const uint4*)g;
  }
  __syncthreads();
  {
    const int d = t >> 2, s0 = (t & 3) * 16;
    u16 tmp[16];
#pragma unroll
    for (int j = 0; j < 16; ++j) tmp[j] = Vs[s0 + j][d];
    u16* dst = Vt + ((size_t)(b * Hc + h) * DKc + d) * Sc + st * 64 + s0;
    *(uint4*)dst = *(const uint4*)tmp;
    *(uint4*)(dst + 8) = *(const uint4*)(tmp + 8);
  }
}

// ---------------- causal flash attention --------------------------------------
// grid (qt=32, h, b), 4 waves, each wave owns 16 q-rows; KBLK=64.
__global__ __launch_bounds__(256)
void attn_k(const u16* __restrict__ Q, const u16* __restrict__ K,
            const u16* __restrict__ Vt, u16* __restrict__ O)
{
  __shared__ u16 Psh[4][16 * 64]; // per-wave P tile, XOR-swizzled
  const int t = threadIdx.x, w = t >> 6, l = t & 63;
  const int l4 = l >> 4, l15 = l & 15;
  const int qt = blockIdx.x, h = blockIdx.y, b = blockIdx.z;
  const size_t bh = (size_t)b * Hc + h;
  const u16* Qb = Q + bh * Sc * DKc;
  const u16* Kb = K + bh * Sc * DKc;
  const u16* Vb = Vt + bh * (size_t)DKc * Sc;
  const int q0 = qt * 64 + w * 16;

  // Q fragments (A-operand), hoisted: row=l&15, k = 8*(l>>4)+j
  const short8 aq0 = *(const short8*)(Qb + (size_t)(q0 + l15) * DKc + l4 * 8);
  const short8 aq1 = *(const short8*)(Qb + (size_t)(q0 + l15) * DKc + 32 + l4 * 8);

  f32x4 o[4] = {};
  float mrow[4] = {-1e30f, -1e30f, -1e30f, -1e30f};
  float lrow[4] = {0.f, 0.f, 0.f, 0.f};
  char* Pw = (char*)&Psh[w][0];

  for (int kt = 0; kt <= qt; ++kt) {
    const int kv0 = kt * 64;
    f32x4 sc[4];
#pragma unroll
    for (int c = 0; c < 4; ++c) { // S = Q*K^T, col-tile c
      const u16* kp = Kb + (size_t)(kv0 + c * 16 + l15) * DKc + l4 * 8;
      short8 k0 = *(const short8*)kp;
      short8 k1 = *(const short8*)(kp + 32);
      f32x4 z = {0.f, 0.f, 0.f, 0.f};
      z = __builtin_amdgcn_mfma_f32_16x16x32_bf16(aq0, k0, z, 0, 0, 0);
      z = __builtin_amdgcn_mfma_f32_16x16x32_bf16(aq1, k1, z, 0, 0, 0);
      sc[c] = z;
    }
    if (kt == qt) { // causal mask on the diagonal tile
#pragma unroll
      for (int c = 0; c < 4; ++c) {
        const int kv = kv0 + c * 16 + l15;
#pragma unroll
        for (int r = 0; r < 4; ++r)
          if (kv > q0 + l4 * 4 + r) sc[c][r] = -1e30f;
      }
    }
    // online softmax: rows live on (l>>4 group, reg); cols across l&15 lanes
    float fac[4];
#pragma unroll
    for (int r = 0; r < 4; ++r) {
      float mx = fmaxf(fmaxf(sc[0][r], sc[1][r]), fmaxf(sc[2][r], sc[3][r]));
      mx = fmaxf(mx, __shfl_xor(mx, 1));
      mx = fmaxf(mx, __shfl_xor(mx, 2));
      mx = fmaxf(mx, __shfl_xor(mx, 4));
      mx = fmaxf(mx, __shfl_xor(mx, 8));
      const float mnew = fmaxf(mrow[r], mx);
      fac[r] = __expf(mrow[r] - mnew);
      float rs = 0.f;
#pragma unroll
      for (int c = 0; c < 4; ++c) {
        const float p = __expf(sc[c][r] - mnew);
        sc[c][r] = p;
        rs += p;
      }
      rs += __shfl_xor(rs, 1);
      rs += __shfl_xor(rs, 2);
      rs += __shfl_xor(rs, 4);
      rs += __shfl_xor(rs, 8);
      lrow[r] = lrow[r] * fac[r] + rs;
      mrow[r] = mnew;
#pragma unroll
      for (int dc = 0; dc < 4; ++dc) o[dc][r] *= fac[r];
    }
    // P -> LDS (bf16, XOR swizzle kills the stride-128B bank conflict)
#pragma unroll
    for (int c = 0; c < 4; ++c)
#pragma unroll
      for (int r = 0; r < 4; ++r) {
        const int row = l4 * 4 + r, col = c * 16 + l15;
        *(u16*)(Pw + ((row * 128 + col * 2) ^ ((row & 7) << 4))) = f2b(sc[c][r]);
      }
    __syncthreads();
    short8 pa0, pa1;
    {
      const int row = l15;
      pa0 = *(const short8*)(Pw + ((row * 128 + l4 * 16) ^ ((row & 7) << 4)));
      pa1 = *(const short8*)(Pw + ((row * 128 + 64 + l4 * 16) ^ ((row & 7) << 4)));
    }
#pragma unroll
    for (int dc = 0; dc < 4; ++dc) { // O += P*V via Vt rows
      const u16* vp = Vb + (size_t)(dc * 16 + l15) * Sc + kv0 + l4 * 8;
      short8 v0 = *(const short8*)vp;
      short8 v1 = *(const short8*)(vp + 32);
      o[dc] = __builtin_amdgcn_mfma_f32_16x16x32_bf16(pa0, v0, o[dc], 0, 0, 0);
      o[dc] = __builtin_amdgcn_mfma_f32_16x16x32_bf16(pa1, v1, o[dc], 0, 0, 0);
    }
  }
#pragma unroll
  for (int dc = 0; dc < 4; ++dc) {
    const int col = h * DKc + dc * 16 + l15;
#pragma unroll
    for (int r = 0; r < 4; ++r) {
      const int srow = q0 + l4 * 4 + r;
      O[(size_t)(b * Sc + srow) * DMc + col] = f2b(o[dc][r] / lrow[r]);
    }
  }
}

// ---------------- launch ------------------------------------------------------
extern "C" void kernel_launch(void* const* d_in, const int* in_sizes, int n_in,
                              void* d_out, int out_size, void* d_ws, size_t ws_size,
                              hipStream_t stream)
{
  const float* x      = (const float*)d_in[0];
  const int*   tokpos = (const int*)d_in[1];
  const float* qkv_w  = (const float*)d_in[2];
  const float* out_w  = (const float*)d_in[3];
  float* out = (float*)d_out;

  char* ws = (char*)d_ws;
  size_t off = 0;
  u16* xb   = (u16*)(ws + off); off += (size_t)Mc * DMc * 2;             // 8.4 MB
  u16* qwb  = (u16*)(ws + off); off += (size_t)3 * DMc * DMc * 2;        // 6.3 MB
  u16* owb  = (u16*)(ws + off); off += (size_t)DMc * DMc * 2;            // 2.1 MB
  u16* qkv  = (u16*)(ws + off); off += (size_t)Mc * 3 * DMc * 2;         // 25.2 MB
  u16* Qr   = (u16*)(ws + off); off += (size_t)Bc * Hc * Sc * DKc * 2;   // 8.4 MB
  u16* Kr   = (u16*)(ws + off); off += (size_t)Bc * Hc * Sc * DKc * 2;   // 8.4 MB
  u16* Vt   = (u16*)(ws + off); off += (size_t)Bc * Hc * DKc * Sc * 2;   // 8.4 MB
  u16* Oa   = (u16*)(ws + off); off += (size_t)Mc * DMc * 2;             // 8.4 MB
  float2* tab = (float2*)(ws + off); off += (size_t)Sc * 32 * sizeof(float2);

  // f32 -> bf16 conversions
  cvt_f32_bf16_k<<<(Mc * DMc / 8 + 255) / 256, 256, 0, stream>>>(x, xb, Mc * DMc / 8);
  cvt_f32_bf16_k<<<(3 * DMc * DMc / 8 + 255) / 256, 256, 0, stream>>>(qkv_w, qwb, 3 * DMc * DMc / 8);
  cvt_f32_bf16_k<<<(DMc * DMc / 8 + 255) / 256, 256, 0, stream>>>(out_w, owb, DMc * DMc / 8);

  rope_table_k<<<(Sc * 32) / 256, 256, 0, stream>>>(tab);
  gemm_bt128<u16><<<dim3(Mc / 128, 3 * DMc / 128), 256, 0, stream>>>(xb, qwb, qkv, Mc, 3 * DMc, DMc);
  rope_reshape_k<<<dim3(Sc / 64, Hc, Bc), 256, 0, stream>>>(qkv, tokpos, tab, Qr, Kr, Vt);
  attn_k<<<dim3(Sc / 64, Hc, Bc), 256, 0, stream>>>(Qr, Kr, Vt, Oa);
  gemm_bt128<float><<<dim3(Mc / 128, DMc / 128), 256, 0, stream>>>(Oa, owb, out, Mc, DMc, DMc);
}

// Round 3
// 217.046 us; speedup vs baseline: 1.8965x; 1.8965x over previous
//
#include <hip/hip_runtime.h>
#include <cstdint>

typedef unsigned short u16;
typedef unsigned int u32;
typedef __attribute__((ext_vector_type(8))) short short8;
typedef __attribute__((ext_vector_type(4))) float f32x4;

static constexpr int Bc = 2, Sc = 2048, DMc = 1024, Hc = 16, DKc = 64;
static constexpr int Mc = Bc * Sc; // 4096

__device__ __forceinline__ float b2f(u16 u) { return __uint_as_float((u32)u << 16); }
__device__ __forceinline__ u16 f2b(float f) {
  u32 x = __float_as_uint(f);
  return (u16)((x + 0x7fffu + ((x >> 16) & 1u)) >> 16);
}
__device__ __forceinline__ u32 pack2(float lo, float hi) {
  return (u32)f2b(lo) | ((u32)f2b(hi) << 16);
}

// ---------------- f32 -> bf16 conversion (RTNE), 8 elems/thread ---------------
__global__ __launch_bounds__(256)
void cvt_f32_bf16_k(const float* __restrict__ src, u16* __restrict__ dst, int n8)
{
  const int i = blockIdx.x * 256 + threadIdx.x;
  if (i >= n8) return;
  const float4 a = *(const float4*)(src + (size_t)i * 8);
  const float4 b = *(const float4*)(src + (size_t)i * 8 + 4);
  uint4 o;
  o.x = pack2(a.x, a.y);
  o.y = pack2(a.z, a.w);
  o.z = pack2(b.x, b.y);
  o.w = pack2(b.z, b.w);
  *(uint4*)(dst + (size_t)i * 8) = o;
}

// ---------------- GEMM: C[M][N] = A[M][K] * W[N][K]^T, bf16 in, f32 acc -------
template <typename OutT>
__global__ __launch_bounds__(256, 2)
void gemm_bt128(const u16* __restrict__ A, const u16* __restrict__ W,
                OutT* __restrict__ C, int M, int N, int K)
{
  __shared__ u16 As[128 * 32];
  __shared__ u16 Bs[128 * 32];
  const int t = threadIdx.x;
  const int w = t >> 6, l = t & 63;
  const int wr = w >> 1, wc = w & 1;
  const int l4 = l >> 4, l15 = l & 15;
  const int bm = blockIdx.x, bn = blockIdx.y;

  f32x4 acc[4][4] = {};

  const int rowA = bm * 128, rowB = bn * 128;
  const int sr = l >> 2, sk = (l & 3) * 8;

  for (int k0 = 0; k0 < K; k0 += 32) {
    __syncthreads();
#pragma unroll
    for (int i = 0; i < 2; ++i) {
      const int chunk = i * 4 + w;
      const u16* ga = A + (size_t)(rowA + chunk * 16 + sr) * K + k0 + sk;
      const u16* gb = W + (size_t)(rowB + chunk * 16 + sr) * K + k0 + sk;
      __builtin_amdgcn_global_load_lds((const __attribute__((address_space(1))) void*)ga,
                                       (__attribute__((address_space(3))) void*)(As + chunk * 512), 16, 0, 0);
      __builtin_amdgcn_global_load_lds((const __attribute__((address_space(1))) void*)gb,
                                       (__attribute__((address_space(3))) void*)(Bs + chunk * 512), 16, 0, 0);
    }
    __syncthreads();
    short8 af[4], bf[4];
#pragma unroll
    for (int m = 0; m < 4; ++m)
      af[m] = *(const short8*)(As + (wr * 64 + m * 16 + l15) * 32 + l4 * 8);
#pragma unroll
    for (int n = 0; n < 4; ++n)
      bf[n] = *(const short8*)(Bs + (wc * 64 + n * 16 + l15) * 32 + l4 * 8);
#pragma unroll
    for (int m = 0; m < 4; ++m)
#pragma unroll
      for (int n = 0; n < 4; ++n)
        acc[m][n] = __builtin_amdgcn_mfma_f32_16x16x32_bf16(af[m], bf[n], acc[m][n], 0, 0, 0);
  }

#pragma unroll
  for (int m = 0; m < 4; ++m) {
    const int r0 = rowA + wr * 64 + m * 16 + l4 * 4;
#pragma unroll
    for (int n = 0; n < 4; ++n) {
      const int c0 = rowB + wc * 64 + n * 16 + l15;
#pragma unroll
      for (int r = 0; r < 4; ++r) {
        const float v = acc[m][n][r];
        if constexpr (sizeof(OutT) == 2)
          C[(size_t)(r0 + r) * N + c0] = (OutT)f2b(v);
        else
          C[(size_t)(r0 + r) * N + c0] = (OutT)v;
      }
    }
  }
}

// ---------------- RoPE cos/sin table: [S][32] float2 --------------------------
__global__ void rope_table_k(float2* __restrict__ tab)
{
  const int idx = blockIdx.x * 256 + threadIdx.x;
  const int p = idx >> 5, i = idx & 31;
  const float invf = powf(10000.0f, -(float)(2 * i) / 64.0f);
  const float ang = (float)p * invf;
  tab[idx] = make_float2(cosf(ang), sinf(ang));
}

// ---------------- RoPE apply + relayout ---------------------------------------
__global__ __launch_bounds__(256)
void rope_reshape_k(const u16* __restrict__ qkv, const int* __restrict__ tokpos,
                    const float2* __restrict__ tab,
                    u16* __restrict__ Q, u16* __restrict__ K, u16* __restrict__ Vt)
{
  __shared__ u16 Vs[64][72];
  const int t = threadIdx.x;
  const int st = blockIdx.x, h = blockIdx.y, b = blockIdx.z;

  {
    const int sl = t >> 2, iq = t & 3;
    const int s = st * 64 + sl;
    const int p = tokpos[b * Sc + s];
    const size_t row = (size_t)(b * Sc + s) * 3 * DMc + h * DKc + iq * 16;
    const size_t orow = ((size_t)(b * Hc + h) * Sc + s) * DKc + iq * 16;
#pragma unroll
    for (int which = 0; which < 2; ++which) {
      const u16* g = qkv + row + which * DMc;
      uint4 va = *(const uint4*)g;
      uint4 vb = *(const uint4*)(g + 8);
      u32 in[8] = {va.x, va.y, va.z, va.w, vb.x, vb.y, vb.z, vb.w};
      const float scale = (which == 0) ? 0.125f : 1.0f;
      u32 ow[8];
#pragma unroll
      for (int j = 0; j < 8; ++j) {
        const float2 cs = tab[p * 32 + iq * 8 + j];
        const float t1 = b2f((u16)(in[j] & 0xffffu));
        const float t2 = b2f((u16)(in[j] >> 16));
        ow[j] = pack2((t1 * cs.x - t2 * cs.y) * scale, (t1 * cs.y + t2 * cs.x) * scale);
      }
      u16* dst = (which == 0 ? Q : K) + orow;
      *(uint4*)dst = make_uint4(ow[0], ow[1], ow[2], ow[3]);
      *(uint4*)(dst + 8) = make_uint4(ow[4], ow[5], ow[6], ow[7]);
    }
  }
#pragma unroll
  for (int it = 0; it < 2; ++it) {
    const int sv = it * 32 + (t >> 3);
    const int d0 = (t & 7) * 8;
    const u16* g = qkv + (size_t)(b * Sc + st * 64 + sv) * 3 * DMc + 2 * DMc + h * DKc + d0;
    *(uint4*)&Vs[sv][d0] = *(const uint4*)g;
  }
  __syncthreads();
  {
    const int d = t >> 2, s0 = (t & 3) * 16;
    u16 tmp[16];
#pragma unroll
    for (int j = 0; j < 16; ++j) tmp[j] = Vs[s0 + j][d];
    u16* dst = Vt + ((size_t)(b * Hc + h) * DKc + d) * Sc + st * 64 + s0;
    *(uint4*)dst = *(const uint4*)tmp;
    *(uint4*)(dst + 8) = *(const uint4*)(tmp + 8);
  }
}

// ---------------- causal flash attention --------------------------------------
// Balanced, barrier-free: grid (32, H, B). Block x: waves 0,1 -> 32 q-rows of
// tile (31 - x/2), waves 2,3 -> 32 q-rows of tile (x/2); sub-half picked by x&1.
// Every block = 33 kv-tile-iters per wave pair; waves fully independent.
__global__ __launch_bounds__(256, 4)
void attn_k(const u16* __restrict__ Q, const u16* __restrict__ K,
            const u16* __restrict__ Vt, u16* __restrict__ O)
{
  __shared__ u16 Psh[4][16 * 64]; // per-wave P tile, XOR-swizzled
  const int t = threadIdx.x, w = t >> 6, l = t & 63;
  const int l4 = l >> 4, l15 = l & 15;
  const int x = blockIdx.x, h = blockIdx.y, b = blockIdx.z;
  const int p = x >> 1;
  const int qt = (w < 2) ? (31 - p) : p;           // heavy tiles on waves 0,1
  const int strip = (x & 1) * 2 + (w & 1);         // 4 strips of 16 rows per tile
  const int q0 = qt * 64 + strip * 16;

  const size_t bh = (size_t)b * Hc + h;
  const u16* Qb = Q + bh * Sc * DKc;
  const u16* Kb = K + bh * Sc * DKc;
  const u16* Vb = Vt + bh * (size_t)DKc * Sc;

  // Q fragments (A-operand), hoisted: row=l&15, k = 8*(l>>4)+j
  const short8 aq0 = *(const short8*)(Qb + (size_t)(q0 + l15) * DKc + l4 * 8);
  const short8 aq1 = *(const short8*)(Qb + (size_t)(q0 + l15) * DKc + 32 + l4 * 8);

  f32x4 o[4] = {};
  float mrow[4] = {-1e30f, -1e30f, -1e30f, -1e30f};
  float lrow[4] = {0.f, 0.f, 0.f, 0.f};
  char* Pw = (char*)&Psh[w][0];

  for (int kt = 0; kt <= qt; ++kt) {
    const int kv0 = kt * 64;
    // K fragments (issued first)
    short8 kf0[4], kf1[4];
#pragma unroll
    for (int c = 0; c < 4; ++c) {
      const u16* kp = Kb + (size_t)(kv0 + c * 16 + l15) * DKc + l4 * 8;
      kf0[c] = *(const short8*)kp;
      kf1[c] = *(const short8*)(kp + 32);
    }
    // V fragments issued NOW so their latency hides under softmax
    short8 vf0[4], vf1[4];
#pragma unroll
    for (int dc = 0; dc < 4; ++dc) {
      const u16* vp = Vb + (size_t)(dc * 16 + l15) * Sc + kv0 + l4 * 8;
      vf0[dc] = *(const short8*)vp;
      vf1[dc] = *(const short8*)(vp + 32);
    }
    f32x4 sc[4];
#pragma unroll
    for (int c = 0; c < 4; ++c) {
      f32x4 z = {0.f, 0.f, 0.f, 0.f};
      z = __builtin_amdgcn_mfma_f32_16x16x32_bf16(aq0, kf0[c], z, 0, 0, 0);
      z = __builtin_amdgcn_mfma_f32_16x16x32_bf16(aq1, kf1[c], z, 0, 0, 0);
      sc[c] = z;
    }
    if (kt == qt) { // causal mask on the diagonal tile
#pragma unroll
      for (int c = 0; c < 4; ++c) {
        const int kv = kv0 + c * 16 + l15;
#pragma unroll
        for (int r = 0; r < 4; ++r)
          if (kv > q0 + l4 * 4 + r) sc[c][r] = -1e30f;
      }
    }
    // online softmax: rows on (l>>4, reg); cols across l&15 lanes
    float fac[4];
#pragma unroll
    for (int r = 0; r < 4; ++r) {
      float mx = fmaxf(fmaxf(sc[0][r], sc[1][r]), fmaxf(sc[2][r], sc[3][r]));
      mx = fmaxf(mx, __shfl_xor(mx, 1));
      mx = fmaxf(mx, __shfl_xor(mx, 2));
      mx = fmaxf(mx, __shfl_xor(mx, 4));
      mx = fmaxf(mx, __shfl_xor(mx, 8));
      const float mnew = fmaxf(mrow[r], mx);
      fac[r] = __expf(mrow[r] - mnew);
      float rs = 0.f;
#pragma unroll
      for (int c = 0; c < 4; ++c) {
        const float pv = __expf(sc[c][r] - mnew);
        sc[c][r] = pv;
        rs += pv;
      }
      rs += __shfl_xor(rs, 1);
      rs += __shfl_xor(rs, 2);
      rs += __shfl_xor(rs, 4);
      rs += __shfl_xor(rs, 8);
      lrow[r] = lrow[r] * fac[r] + rs;
      mrow[r] = mnew;
#pragma unroll
      for (int dc = 0; dc < 4; ++dc) o[dc][r] *= fac[r];
    }
    // P -> per-wave LDS (XOR swizzle); intra-wave only -> NO barrier needed
#pragma unroll
    for (int c = 0; c < 4; ++c)
#pragma unroll
      for (int r = 0; r < 4; ++r) {
        const int row = l4 * 4 + r, col = c * 16 + l15;
        *(u16*)(Pw + ((row * 128 + col * 2) ^ ((row & 7) << 4))) = f2b(sc[c][r]);
      }
    short8 pa0, pa1;
    {
      const int row = l15;
      pa0 = *(const short8*)(Pw + ((row * 128 + l4 * 16) ^ ((row & 7) << 4)));
      pa1 = *(const short8*)(Pw + ((row * 128 + 64 + l4 * 16) ^ ((row & 7) << 4)));
    }
#pragma unroll
    for (int dc = 0; dc < 4; ++dc) {
      o[dc] = __builtin_amdgcn_mfma_f32_16x16x32_bf16(pa0, vf0[dc], o[dc], 0, 0, 0);
      o[dc] = __builtin_amdgcn_mfma_f32_16x16x32_bf16(pa1, vf1[dc], o[dc], 0, 0, 0);
    }
  }
#pragma unroll
  for (int dc = 0; dc < 4; ++dc) {
    const int col = h * DKc + dc * 16 + l15;
#pragma unroll
    for (int r = 0; r < 4; ++r) {
      const int srow = q0 + l4 * 4 + r;
      O[(size_t)(b * Sc + srow) * DMc + col] = f2b(o[dc][r] / lrow[r]);
    }
  }
}

// ---------------- launch ------------------------------------------------------
extern "C" void kernel_launch(void* const* d_in, const int* in_sizes, int n_in,
                              void* d_out, int out_size, void* d_ws, size_t ws_size,
                              hipStream_t stream)
{
  const float* x      = (const float*)d_in[0];
  const int*   tokpos = (const int*)d_in[1];
  const float* qkv_w  = (const float*)d_in[2];
  const float* out_w  = (const float*)d_in[3];
  float* out = (float*)d_out;

  char* ws = (char*)d_ws;
  size_t off = 0;
  u16* xb   = (u16*)(ws + off); off += (size_t)Mc * DMc * 2;
  u16* qwb  = (u16*)(ws + off); off += (size_t)3 * DMc * DMc * 2;
  u16* owb  = (u16*)(ws + off); off += (size_t)DMc * DMc * 2;
  u16* qkv  = (u16*)(ws + off); off += (size_t)Mc * 3 * DMc * 2;
  u16* Qr   = (u16*)(ws + off); off += (size_t)Bc * Hc * Sc * DKc * 2;
  u16* Kr   = (u16*)(ws + off); off += (size_t)Bc * Hc * Sc * DKc * 2;
  u16* Vt   = (u16*)(ws + off); off += (size_t)Bc * Hc * DKc * Sc * 2;
  u16* Oa   = (u16*)(ws + off); off += (size_t)Mc * DMc * 2;
  float2* tab = (float2*)(ws + off); off += (size_t)Sc * 32 * sizeof(float2);

  cvt_f32_bf16_k<<<(Mc * DMc / 8 + 255) / 256, 256, 0, stream>>>(x, xb, Mc * DMc / 8);
  cvt_f32_bf16_k<<<(3 * DMc * DMc / 8 + 255) / 256, 256, 0, stream>>>(qkv_w, qwb, 3 * DMc * DMc / 8);
  cvt_f32_bf16_k<<<(DMc * DMc / 8 + 255) / 256, 256, 0, stream>>>(out_w, owb, DMc * DMc / 8);

  rope_table_k<<<(Sc * 32) / 256, 256, 0, stream>>>(tab);
  gemm_bt128<u16><<<dim3(Mc / 128, 3 * DMc / 128), 256, 0, stream>>>(xb, qwb, qkv, Mc, 3 * DMc, DMc);
  rope_reshape_k<<<dim3(Sc / 64, Hc, Bc), 256, 0, stream>>>(qkv, tokpos, tab, Qr, Kr, Vt);
  attn_k<<<dim3(32, Hc, Bc), 256, 0, stream>>>(Qr, Kr, Vt, Oa);
  gemm_bt128<float><<<dim3(Mc / 128, DMc / 128), 256, 0, stream>>>(Oa, owb, out, Mc, DMc, DMc);
}

// Round 4
// 210.042 us; speedup vs baseline: 1.9598x; 1.0333x over previous
//
#include <hip/hip_runtime.h>
#include <cstdint>

typedef unsigned short u16;
typedef unsigned int u32;
typedef __attribute__((ext_vector_type(8))) short short8;
typedef __attribute__((ext_vector_type(4))) float f32x4;

static constexpr int Bc = 2, Sc = 2048, DMc = 1024, Hc = 16, DKc = 64;
static constexpr int Mc = Bc * Sc; // 4096

__device__ __forceinline__ float b2f(u16 u) { return __uint_as_float((u32)u << 16); }
__device__ __forceinline__ u16 f2b(float f) {
  u32 x = __float_as_uint(f);
  return (u16)((x + 0x7fffu + ((x >> 16) & 1u)) >> 16);
}
__device__ __forceinline__ u32 pack2(float lo, float hi) {
  return (u32)f2b(lo) | ((u32)f2b(hi) << 16);
}

// ---------------- f32 -> bf16 conversion (RTNE), 8 elems/thread ---------------
__global__ __launch_bounds__(256)
void cvt_f32_bf16_k(const float* __restrict__ src, u16* __restrict__ dst, int n8)
{
  const int i = blockIdx.x * 256 + threadIdx.x;
  if (i >= n8) return;
  const float4 a = *(const float4*)(src + (size_t)i * 8);
  const float4 b = *(const float4*)(src + (size_t)i * 8 + 4);
  uint4 o;
  o.x = pack2(a.x, a.y);
  o.y = pack2(a.z, a.w);
  o.z = pack2(b.x, b.y);
  o.w = pack2(b.z, b.w);
  *(uint4*)(dst + (size_t)i * 8) = o;
}

// ---------------- GEMM: C[M][N] = A[M][K] * W[N][K]^T, bf16 in, f32 acc -------
template <typename OutT>
__global__ __launch_bounds__(256, 2)
void gemm_bt128(const u16* __restrict__ A, const u16* __restrict__ W,
                OutT* __restrict__ C, int M, int N, int K)
{
  __shared__ u16 As[128 * 32];
  __shared__ u16 Bs[128 * 32];
  const int t = threadIdx.x;
  const int w = t >> 6, l = t & 63;
  const int wr = w >> 1, wc = w & 1;
  const int l4 = l >> 4, l15 = l & 15;
  const int bm = blockIdx.x, bn = blockIdx.y;

  f32x4 acc[4][4] = {};

  const int rowA = bm * 128, rowB = bn * 128;
  const int sr = l >> 2, sk = (l & 3) * 8;

  for (int k0 = 0; k0 < K; k0 += 32) {
    __syncthreads();
#pragma unroll
    for (int i = 0; i < 2; ++i) {
      const int chunk = i * 4 + w;
      const u16* ga = A + (size_t)(rowA + chunk * 16 + sr) * K + k0 + sk;
      const u16* gb = W + (size_t)(rowB + chunk * 16 + sr) * K + k0 + sk;
      __builtin_amdgcn_global_load_lds((const __attribute__((address_space(1))) void*)ga,
                                       (__attribute__((address_space(3))) void*)(As + chunk * 512), 16, 0, 0);
      __builtin_amdgcn_global_load_lds((const __attribute__((address_space(1))) void*)gb,
                                       (__attribute__((address_space(3))) void*)(Bs + chunk * 512), 16, 0, 0);
    }
    __syncthreads();
    short8 af[4], bf[4];
#pragma unroll
    for (int m = 0; m < 4; ++m)
      af[m] = *(const short8*)(As + (wr * 64 + m * 16 + l15) * 32 + l4 * 8);
#pragma unroll
    for (int n = 0; n < 4; ++n)
      bf[n] = *(const short8*)(Bs + (wc * 64 + n * 16 + l15) * 32 + l4 * 8);
#pragma unroll
    for (int m = 0; m < 4; ++m)
#pragma unroll
      for (int n = 0; n < 4; ++n)
        acc[m][n] = __builtin_amdgcn_mfma_f32_16x16x32_bf16(af[m], bf[n], acc[m][n], 0, 0, 0);
  }

#pragma unroll
  for (int m = 0; m < 4; ++m) {
    const int r0 = rowA + wr * 64 + m * 16 + l4 * 4;
#pragma unroll
    for (int n = 0; n < 4; ++n) {
      const int c0 = rowB + wc * 64 + n * 16 + l15;
#pragma unroll
      for (int r = 0; r < 4; ++r) {
        const float v = acc[m][n][r];
        if constexpr (sizeof(OutT) == 2)
          C[(size_t)(r0 + r) * N + c0] = (OutT)f2b(v);
        else
          C[(size_t)(r0 + r) * N + c0] = (OutT)v;
      }
    }
  }
}

// ---------------- RoPE cos/sin table: [S][32] float2 --------------------------
__global__ void rope_table_k(float2* __restrict__ tab)
{
  const int idx = blockIdx.x * 256 + threadIdx.x;
  const int p = idx >> 5, i = idx & 31;
  const float invf = powf(10000.0f, -(float)(2 * i) / 64.0f);
  const float ang = (float)p * invf;
  tab[idx] = make_float2(cosf(ang), sinf(ang));
}

// ---------------- RoPE apply + relayout ---------------------------------------
__global__ __launch_bounds__(256)
void rope_reshape_k(const u16* __restrict__ qkv, const int* __restrict__ tokpos,
                    const float2* __restrict__ tab,
                    u16* __restrict__ Q, u16* __restrict__ K, u16* __restrict__ Vt)
{
  __shared__ u16 Vs[64][72];
  const int t = threadIdx.x;
  const int st = blockIdx.x, h = blockIdx.y, b = blockIdx.z;

  {
    const int sl = t >> 2, iq = t & 3;
    const int s = st * 64 + sl;
    const int p = tokpos[b * Sc + s];
    const size_t row = (size_t)(b * Sc + s) * 3 * DMc + h * DKc + iq * 16;
    const size_t orow = ((size_t)(b * Hc + h) * Sc + s) * DKc + iq * 16;
#pragma unroll
    for (int which = 0; which < 2; ++which) {
      const u16* g = qkv + row + which * DMc;
      uint4 va = *(const uint4*)g;
      uint4 vb = *(const uint4*)(g + 8);
      u32 in[8] = {va.x, va.y, va.z, va.w, vb.x, vb.y, vb.z, vb.w};
      const float scale = (which == 0) ? 0.125f : 1.0f;
      u32 ow[8];
#pragma unroll
      for (int j = 0; j < 8; ++j) {
        const float2 cs = tab[p * 32 + iq * 8 + j];
        const float t1 = b2f((u16)(in[j] & 0xffffu));
        const float t2 = b2f((u16)(in[j] >> 16));
        ow[j] = pack2((t1 * cs.x - t2 * cs.y) * scale, (t1 * cs.y + t2 * cs.x) * scale);
      }
      u16* dst = (which == 0 ? Q : K) + orow;
      *(uint4*)dst = make_uint4(ow[0], ow[1], ow[2], ow[3]);
      *(uint4*)(dst + 8) = make_uint4(ow[4], ow[5], ow[6], ow[7]);
    }
  }
#pragma unroll
  for (int it = 0; it < 2; ++it) {
    const int sv = it * 32 + (t >> 3);
    const int d0 = (t & 7) * 8;
    const u16* g = qkv + (size_t)(b * Sc + st * 64 + sv) * 3 * DMc + 2 * DMc + h * DKc + d0;
    *(uint4*)&Vs[sv][d0] = *(const uint4*)g;
  }
  __syncthreads();
  {
    const int d = t >> 2, s0 = (t & 3) * 16;
    u16 tmp[16];
#pragma unroll
    for (int j = 0; j < 16; ++j) tmp[j] = Vs[s0 + j][d];
    u16* dst = Vt + ((size_t)(b * Hc + h) * DKc + d) * Sc + st * 64 + s0;
    *(uint4*)dst = *(const uint4*)tmp;
    *(uint4*)(dst + 8) = *(const uint4*)(tmp + 8);
  }
}

// ---------------- causal flash attention --------------------------------------
// Balanced, barrier-free, XCD-swizzled. Logical grid 1024 blocks; hw linear id
// remapped (bid%8)*128 + bid/8 so each XCD owns 4 consecutive (b,h) pairs ->
// K+V working set 2 MB fits the 4 MB per-XCD L2 (T1, bijective since 1024%8==0).
__global__ __launch_bounds__(256, 4)
void attn_k(const u16* __restrict__ Q, const u16* __restrict__ K,
            const u16* __restrict__ Vt, u16* __restrict__ O)
{
  __shared__ u16 Psh[4][16 * 64]; // per-wave P tile, XOR-swizzled
  const int t = threadIdx.x, w = t >> 6, l = t & 63;
  const int l4 = l >> 4, l15 = l & 15;

  int bid = blockIdx.x + 32 * (blockIdx.y + Hc * blockIdx.z);
  bid = (bid & 7) * 128 + (bid >> 3); // XCD-contiguous remap
  const int x = bid & 31, h = (bid >> 5) & 15, b = bid >> 9;

  const int p = x >> 1;
  const int qt = (w < 2) ? (31 - p) : p;           // heavy tiles on waves 0,1
  const int strip = (x & 1) * 2 + (w & 1);         // 4 strips of 16 rows per tile
  const int q0 = qt * 64 + strip * 16;

  const size_t bh = (size_t)b * Hc + h;
  const u16* Qb = Q + bh * Sc * DKc;
  const u16* Kb = K + bh * Sc * DKc;
  const u16* Vb = Vt + bh * (size_t)DKc * Sc;

  // Q fragments (A-operand), hoisted: row=l&15, k = 8*(l>>4)+j
  const short8 aq0 = *(const short8*)(Qb + (size_t)(q0 + l15) * DKc + l4 * 8);
  const short8 aq1 = *(const short8*)(Qb + (size_t)(q0 + l15) * DKc + 32 + l4 * 8);

  f32x4 o[4] = {};
  float mrow[4] = {-1e30f, -1e30f, -1e30f, -1e30f};
  float lrow[4] = {0.f, 0.f, 0.f, 0.f};
  char* Pw = (char*)&Psh[w][0];

  for (int kt = 0; kt <= qt; ++kt) {
    const int kv0 = kt * 64;
    short8 kf0[4], kf1[4];
#pragma unroll
    for (int c = 0; c < 4; ++c) {
      const u16* kp = Kb + (size_t)(kv0 + c * 16 + l15) * DKc + l4 * 8;
      kf0[c] = *(const short8*)kp;
      kf1[c] = *(const short8*)(kp + 32);
    }
    short8 vf0[4], vf1[4];
#pragma unroll
    for (int dc = 0; dc < 4; ++dc) {
      const u16* vp = Vb + (size_t)(dc * 16 + l15) * Sc + kv0 + l4 * 8;
      vf0[dc] = *(const short8*)vp;
      vf1[dc] = *(const short8*)(vp + 32);
    }
    f32x4 sc[4];
#pragma unroll
    for (int c = 0; c < 4; ++c) {
      f32x4 z = {0.f, 0.f, 0.f, 0.f};
      z = __builtin_amdgcn_mfma_f32_16x16x32_bf16(aq0, kf0[c], z, 0, 0, 0);
      z = __builtin_amdgcn_mfma_f32_16x16x32_bf16(aq1, kf1[c], z, 0, 0, 0);
      sc[c] = z;
    }
    if (kt == qt) { // causal mask on the diagonal tile
#pragma unroll
      for (int c = 0; c < 4; ++c) {
        const int kv = kv0 + c * 16 + l15;
#pragma unroll
        for (int r = 0; r < 4; ++r)
          if (kv > q0 + l4 * 4 + r) sc[c][r] = -1e30f;
      }
    }
    float fac[4];
#pragma unroll
    for (int r = 0; r < 4; ++r) {
      float mx = fmaxf(fmaxf(sc[0][r], sc[1][r]), fmaxf(sc[2][r], sc[3][r]));
      mx = fmaxf(mx, __shfl_xor(mx, 1));
      mx = fmaxf(mx, __shfl_xor(mx, 2));
      mx = fmaxf(mx, __shfl_xor(mx, 4));
      mx = fmaxf(mx, __shfl_xor(mx, 8));
      const float mnew = fmaxf(mrow[r], mx);
      fac[r] = __expf(mrow[r] - mnew);
      float rs = 0.f;
#pragma unroll
      for (int c = 0; c < 4; ++c) {
        const float pv = __expf(sc[c][r] - mnew);
        sc[c][r] = pv;
        rs += pv;
      }
      rs += __shfl_xor(rs, 1);
      rs += __shfl_xor(rs, 2);
      rs += __shfl_xor(rs, 4);
      rs += __shfl_xor(rs, 8);
      lrow[r] = lrow[r] * fac[r] + rs;
      mrow[r] = mnew;
#pragma unroll
      for (int dc = 0; dc < 4; ++dc) o[dc][r] *= fac[r];
    }
    // P -> per-wave LDS (XOR swizzle); intra-wave only -> NO barrier needed
#pragma unroll
    for (int c = 0; c < 4; ++c)
#pragma unroll
      for (int r = 0; r < 4; ++r) {
        const int row = l4 * 4 + r, col = c * 16 + l15;
        *(u16*)(Pw + ((row * 128 + col * 2) ^ ((row & 7) << 4))) = f2b(sc[c][r]);
      }
    short8 pa0, pa1;
    {
      const int row = l15;
      pa0 = *(const short8*)(Pw + ((row * 128 + l4 * 16) ^ ((row & 7) << 4)));
      pa1 = *(const short8*)(Pw + ((row * 128 + 64 + l4 * 16) ^ ((row & 7) << 4)));
    }
#pragma unroll
    for (int dc = 0; dc < 4; ++dc) {
      o[dc] = __builtin_amdgcn_mfma_f32_16x16x32_bf16(pa0, vf0[dc], o[dc], 0, 0, 0);
      o[dc] = __builtin_amdgcn_mfma_f32_16x16x32_bf16(pa1, vf1[dc], o[dc], 0, 0, 0);
    }
  }
#pragma unroll
  for (int dc = 0; dc < 4; ++dc) {
    const int col = h * DKc + dc * 16 + l15;
#pragma unroll
    for (int r = 0; r < 4; ++r) {
      const int srow = q0 + l4 * 4 + r;
      O[(size_t)(b * Sc + srow) * DMc + col] = f2b(o[dc][r] / lrow[r]);
    }
  }
}

// ---------------- launch ------------------------------------------------------
extern "C" void kernel_launch(void* const* d_in, const int* in_sizes, int n_in,
                              void* d_out, int out_size, void* d_ws, size_t ws_size,
                              hipStream_t stream)
{
  const float* x      = (const float*)d_in[0];
  const int*   tokpos = (const int*)d_in[1];
  const float* qkv_w  = (const float*)d_in[2];
  const float* out_w  = (const float*)d_in[3];
  float* out = (float*)d_out;

  char* ws = (char*)d_ws;
  size_t off = 0;
  u16* xb   = (u16*)(ws + off); off += (size_t)Mc * DMc * 2;
  u16* qwb  = (u16*)(ws + off); off += (size_t)3 * DMc * DMc * 2;
  u16* owb  = (u16*)(ws + off); off += (size_t)DMc * DMc * 2;
  u16* qkv  = (u16*)(ws + off); off += (size_t)Mc * 3 * DMc * 2;
  u16* Qr   = (u16*)(ws + off); off += (size_t)Bc * Hc * Sc * DKc * 2;
  u16* Kr   = (u16*)(ws + off); off += (size_t)Bc * Hc * Sc * DKc * 2;
  u16* Vt   = (u16*)(ws + off); off += (size_t)Bc * Hc * DKc * Sc * 2;
  u16* Oa   = (u16*)(ws + off); off += (size_t)Mc * DMc * 2;
  float2* tab = (float2*)(ws + off); off += (size_t)Sc * 32 * sizeof(float2);

  cvt_f32_bf16_k<<<(Mc * DMc / 8 + 255) / 256, 256, 0, stream>>>(x, xb, Mc * DMc / 8);
  cvt_f32_bf16_k<<<(3 * DMc * DMc / 8 + 255) / 256, 256, 0, stream>>>(qkv_w, qwb, 3 * DMc * DMc / 8);
  cvt_f32_bf16_k<<<(DMc * DMc / 8 + 255) / 256, 256, 0, stream>>>(out_w, owb, DMc * DMc / 8);

  rope_table_k<<<(Sc * 32) / 256, 256, 0, stream>>>(tab);
  gemm_bt128<u16><<<dim3(Mc / 128, 3 * DMc / 128), 256, 0, stream>>>(xb, qwb, qkv, Mc, 3 * DMc, DMc);
  rope_reshape_k<<<dim3(Sc / 64, Hc, Bc), 256, 0, stream>>>(qkv, tokpos, tab, Qr, Kr, Vt);
  attn_k<<<dim3(32, Hc, Bc), 256, 0, stream>>>(Qr, Kr, Vt, Oa);
  gemm_bt128<float><<<dim3(Mc / 128, DMc / 128), 256, 0, stream>>>(Oa, owb, out, Mc, DMc, DMc);
}

// Round 5
// 208.058 us; speedup vs baseline: 1.9785x; 1.0095x over previous
//
#include <hip/hip_runtime.h>
#include <cstdint>

typedef unsigned short u16;
typedef unsigned int u32;
typedef __attribute__((ext_vector_type(8))) short short8;
typedef __attribute__((ext_vector_type(4))) float f32x4;

static constexpr int Bc = 2, Sc = 2048, DMc = 1024, Hc = 16, DKc = 64;
static constexpr int Mc = Bc * Sc; // 4096

__device__ __forceinline__ float b2f(u16 u) { return __uint_as_float((u32)u << 16); }
__device__ __forceinline__ u16 f2b(float f) {
  u32 x = __float_as_uint(f);
  return (u16)((x + 0x7fffu + ((x >> 16) & 1u)) >> 16);
}
__device__ __forceinline__ u32 pack2(float lo, float hi) {
  return (u32)f2b(lo) | ((u32)f2b(hi) << 16);
}

// ---------------- f32 -> bf16 conversion (RTNE), 8 elems/thread ---------------
__global__ __launch_bounds__(256)
void cvt_f32_bf16_k(const float* __restrict__ src, u16* __restrict__ dst, int n8)
{
  const int i = blockIdx.x * 256 + threadIdx.x;
  if (i >= n8) return;
  const float4 a = *(const float4*)(src + (size_t)i * 8);
  const float4 b = *(const float4*)(src + (size_t)i * 8 + 4);
  uint4 o;
  o.x = pack2(a.x, a.y);
  o.y = pack2(a.z, a.w);
  o.z = pack2(b.x, b.y);
  o.w = pack2(b.z, b.w);
  *(uint4*)(dst + (size_t)i * 8) = o;
}

// ---------------- GEMM: C[M][N] = A[M][K] * W[N][K]^T, bf16 in, f32 acc -------
template <typename OutT>
__global__ __launch_bounds__(256, 2)
void gemm_bt128(const u16* __restrict__ A, const u16* __restrict__ W,
                OutT* __restrict__ C, int M, int N, int K)
{
  __shared__ u16 As[128 * 32];
  __shared__ u16 Bs[128 * 32];
  const int t = threadIdx.x;
  const int w = t >> 6, l = t & 63;
  const int wr = w >> 1, wc = w & 1;
  const int l4 = l >> 4, l15 = l & 15;
  const int bm = blockIdx.x, bn = blockIdx.y;

  f32x4 acc[4][4] = {};

  const int rowA = bm * 128, rowB = bn * 128;
  const int sr = l >> 2, sk = (l & 3) * 8;

  for (int k0 = 0; k0 < K; k0 += 32) {
    __syncthreads();
#pragma unroll
    for (int i = 0; i < 2; ++i) {
      const int chunk = i * 4 + w;
      const u16* ga = A + (size_t)(rowA + chunk * 16 + sr) * K + k0 + sk;
      const u16* gb = W + (size_t)(rowB + chunk * 16 + sr) * K + k0 + sk;
      __builtin_amdgcn_global_load_lds((const __attribute__((address_space(1))) void*)ga,
                                       (__attribute__((address_space(3))) void*)(As + chunk * 512), 16, 0, 0);
      __builtin_amdgcn_global_load_lds((const __attribute__((address_space(1))) void*)gb,
                                       (__attribute__((address_space(3))) void*)(Bs + chunk * 512), 16, 0, 0);
    }
    __syncthreads();
    short8 af[4], bf[4];
#pragma unroll
    for (int m = 0; m < 4; ++m)
      af[m] = *(const short8*)(As + (wr * 64 + m * 16 + l15) * 32 + l4 * 8);
#pragma unroll
    for (int n = 0; n < 4; ++n)
      bf[n] = *(const short8*)(Bs + (wc * 64 + n * 16 + l15) * 32 + l4 * 8);
#pragma unroll
    for (int m = 0; m < 4; ++m)
#pragma unroll
      for (int n = 0; n < 4; ++n)
        acc[m][n] = __builtin_amdgcn_mfma_f32_16x16x32_bf16(af[m], bf[n], acc[m][n], 0, 0, 0);
  }

#pragma unroll
  for (int m = 0; m < 4; ++m) {
    const int r0 = rowA + wr * 64 + m * 16 + l4 * 4;
#pragma unroll
    for (int n = 0; n < 4; ++n) {
      const int c0 = rowB + wc * 64 + n * 16 + l15;
#pragma unroll
      for (int r = 0; r < 4; ++r) {
        const float v = acc[m][n][r];
        if constexpr (sizeof(OutT) == 2)
          C[(size_t)(r0 + r) * N + c0] = (OutT)f2b(v);
        else
          C[(size_t)(r0 + r) * N + c0] = (OutT)v;
      }
    }
  }
}

// ---------------- RoPE cos/sin table: [S][32] float2 --------------------------
__global__ void rope_table_k(float2* __restrict__ tab)
{
  const int idx = blockIdx.x * 256 + threadIdx.x;
  const int p = idx >> 5, i = idx & 31;
  const float invf = powf(10000.0f, -(float)(2 * i) / 64.0f);
  const float ang = (float)p * invf;
  tab[idx] = make_float2(cosf(ang), sinf(ang));
}

// ---------------- RoPE apply + relayout ---------------------------------------
__global__ __launch_bounds__(256)
void rope_reshape_k(const u16* __restrict__ qkv, const int* __restrict__ tokpos,
                    const float2* __restrict__ tab,
                    u16* __restrict__ Q, u16* __restrict__ K, u16* __restrict__ Vt)
{
  __shared__ u16 Vs[64][72];
  const int t = threadIdx.x;
  const int st = blockIdx.x, h = blockIdx.y, b = blockIdx.z;

  {
    const int sl = t >> 2, iq = t & 3;
    const int s = st * 64 + sl;
    const int p = tokpos[b * Sc + s];
    const size_t row = (size_t)(b * Sc + s) * 3 * DMc + h * DKc + iq * 16;
    const size_t orow = ((size_t)(b * Hc + h) * Sc + s) * DKc + iq * 16;
#pragma unroll
    for (int which = 0; which < 2; ++which) {
      const u16* g = qkv + row + which * DMc;
      uint4 va = *(const uint4*)g;
      uint4 vb = *(const uint4*)(g + 8);
      u32 in[8] = {va.x, va.y, va.z, va.w, vb.x, vb.y, vb.z, vb.w};
      const float scale = (which == 0) ? 0.125f : 1.0f;
      u32 ow[8];
#pragma unroll
      for (int j = 0; j < 8; ++j) {
        const float2 cs = tab[p * 32 + iq * 8 + j];
        const float t1 = b2f((u16)(in[j] & 0xffffu));
        const float t2 = b2f((u16)(in[j] >> 16));
        ow[j] = pack2((t1 * cs.x - t2 * cs.y) * scale, (t1 * cs.y + t2 * cs.x) * scale);
      }
      u16* dst = (which == 0 ? Q : K) + orow;
      *(uint4*)dst = make_uint4(ow[0], ow[1], ow[2], ow[3]);
      *(uint4*)(dst + 8) = make_uint4(ow[4], ow[5], ow[6], ow[7]);
    }
  }
#pragma unroll
  for (int it = 0; it < 2; ++it) {
    const int sv = it * 32 + (t >> 3);
    const int d0 = (t & 7) * 8;
    const u16* g = qkv + (size_t)(b * Sc + st * 64 + sv) * 3 * DMc + 2 * DMc + h * DKc + d0;
    *(uint4*)&Vs[sv][d0] = *(const uint4*)g;
  }
  __syncthreads();
  {
    const int d = t >> 2, s0 = (t & 3) * 16;
    u16 tmp[16];
#pragma unroll
    for (int j = 0; j < 16; ++j) tmp[j] = Vs[s0 + j][d];
    u16* dst = Vt + ((size_t)(b * Hc + h) * DKc + d) * Sc + st * 64 + s0;
    *(uint4*)dst = *(const uint4*)tmp;
    *(uint4*)(dst + 8) = *(const uint4*)(tmp + 8);
  }
}

// ---------------- causal flash attention (swapped-QK^T, uniform waves) --------
// grid (16, H, B) = 512 blocks x 4 waves. Wave = strip w (16 q-rows) of tile
// pair (31-p, p): exactly 17 kv-iters of KBLK=128 for EVERY wave (no SIMD
// imbalance possible). S^T = mfma(K_frag, Q_frag): kv on (l4*4+reg), q on l15
// -> softmax is in-lane + 2 shfl per reduction. P staged per-wave in LDS
// (swizzled) in exactly the PV A-frag layout. fac/lsum cross lane->reg domain
// via a 16-float LDS broadcast. XCD remap keeps 4 (b,h) per XCD L2.
__global__ __launch_bounds__(256, 2)
void attn_k(const u16* __restrict__ Q, const u16* __restrict__ K,
            const u16* __restrict__ Vt, u16* __restrict__ O)
{
  __shared__ u16 Psh[4][16 * 128]; // per-wave P tile (4 KB each), XOR-swizzled
  __shared__ float Fsh[4][16];     // per-wave lane->reg redistribution
  const int t = threadIdx.x, w = t >> 6, l = t & 63;
  const int l4 = l >> 4, l15 = l & 15;

  int bid = blockIdx.x + 16 * (blockIdx.y + Hc * blockIdx.z);
  bid = (bid & 7) * 64 + (bid >> 3); // XCD-contiguous remap (bijective: 512%8==0)
  const int p = bid & 15, h = (bid >> 4) & 15, b = bid >> 8;

  const size_t bh = (size_t)b * Hc + h;
  const u16* Qb = Q + bh * Sc * DKc;
  const u16* Kb = K + bh * Sc * DKc;
  const u16* Vb = Vt + bh * (size_t)DKc * Sc;
  char* Pw = (char*)&Psh[w][0];
  float* Fw = &Fsh[w][0];
  const int swz = (l15 & 7) << 4;

#pragma unroll
  for (int seg = 0; seg < 2; ++seg) {
    const int qt = seg ? p : 31 - p;
    const int q0 = qt * 64 + w * 16;
    const int niter = (qt + 2) >> 1; // ceil((qt+1)*64 / 128)

    // Q B-frags: row(q)=l15, k(d)=8*l4+j
    const short8 qf0 = *(const short8*)(Qb + (size_t)(q0 + l15) * DKc + l4 * 8);
    const short8 qf1 = *(const short8*)(Qb + (size_t)(q0 + l15) * DKc + 32 + l4 * 8);

    f32x4 o[4] = {};
    float m = -1e30f, lsum = 0.f;

    for (int it = 0; it < niter; ++it) {
      const int kv0 = it * 128;
      // K A-frags: 8 kv-subtiles x 2 d-halves
      short8 ka[8], kb2[8];
#pragma unroll
      for (int c = 0; c < 8; ++c) {
        const u16* kp = Kb + (size_t)(kv0 + c * 16 + l15) * DKc + l4 * 8;
        ka[c] = *(const short8*)kp;
        kb2[c] = *(const short8*)(kp + 32);
      }
      // V B-frags (row(d)=l15, k(kv)=8*l4+j), issued early to hide latency
      short8 vf[4][4];
#pragma unroll
      for (int kv2 = 0; kv2 < 4; ++kv2)
#pragma unroll
        for (int dc = 0; dc < 4; ++dc)
          vf[kv2][dc] = *(const short8*)(Vb + (size_t)(dc * 16 + l15) * Sc + kv0 + kv2 * 32 + l4 * 8);

      // S^T tile: kv = kv0 + c*16 + l4*4 + r, q = q0 + l15
      f32x4 sc[8];
#pragma unroll
      for (int c = 0; c < 8; ++c) {
        f32x4 z = {0.f, 0.f, 0.f, 0.f};
        z = __builtin_amdgcn_mfma_f32_16x16x32_bf16(ka[c], qf0, z, 0, 0, 0);
        z = __builtin_amdgcn_mfma_f32_16x16x32_bf16(kb2[c], qf1, z, 0, 0, 0);
        sc[c] = z;
      }
      if (kv0 + 127 > q0) { // causal mask (wave-uniform trigger)
#pragma unroll
        for (int c = 0; c < 8; ++c) {
          const int kvr = kv0 + c * 16 + l4 * 4;
#pragma unroll
          for (int r = 0; r < 4; ++r)
            if (kvr + r > q0 + l15) sc[c][r] = -1e30f;
        }
      }
      // online softmax: all in-lane + 2 shfl per reduction
      float pmax = -1e30f;
#pragma unroll
      for (int c = 0; c < 8; ++c)
        pmax = fmaxf(pmax, fmaxf(fmaxf(sc[c][0], sc[c][1]), fmaxf(sc[c][2], sc[c][3])));
      pmax = fmaxf(pmax, __shfl_xor(pmax, 16));
      pmax = fmaxf(pmax, __shfl_xor(pmax, 32));
      const float mnew = fmaxf(m, pmax);
      const float fac = __expf(m - mnew);
      float rs = 0.f;
#pragma unroll
      for (int c = 0; c < 8; ++c) {
        const float p0 = __expf(sc[c][0] - mnew);
        const float p1 = __expf(sc[c][1] - mnew);
        const float p2 = __expf(sc[c][2] - mnew);
        const float p3 = __expf(sc[c][3] - mnew);
        rs += (p0 + p1) + (p2 + p3);
        uint2 pk;
        pk.x = pack2(p0, p1);
        pk.y = pack2(p2, p3);
        // P[q=l15][kv_local = c*16 + l4*4 + 0..3] (bf16), swizzled
        *(uint2*)(Pw + ((l15 * 256 + c * 32 + l4 * 8) ^ swz)) = pk;
      }
      rs += __shfl_xor(rs, 16);
      rs += __shfl_xor(rs, 32);
      lsum = lsum * fac + rs;
      m = mnew;
      // fac: lane-domain (q=l15) -> reg-domain (q=l4*4+r)
      Fw[l15] = fac;
      const f32x4 f4 = *(const f32x4*)&Fw[l4 * 4];
#pragma unroll
      for (int dc = 0; dc < 4; ++dc) {
        o[dc][0] *= f4[0]; o[dc][1] *= f4[1];
        o[dc][2] *= f4[2]; o[dc][3] *= f4[3];
      }
      // PV: A-frag = P rows (q=l15, kv=kv2*32+8*l4+j) straight from LDS
#pragma unroll
      for (int kv2 = 0; kv2 < 4; ++kv2) {
        const short8 pa = *(const short8*)(Pw + ((l15 * 256 + kv2 * 64 + l4 * 16) ^ swz));
#pragma unroll
        for (int dc = 0; dc < 4; ++dc)
          o[dc] = __builtin_amdgcn_mfma_f32_16x16x32_bf16(pa, vf[kv2][dc], o[dc], 0, 0, 0);
      }
    }
    // epilogue: lsum lane->reg, normalize, store (O rows q=q0+l4*4+r, d=dc*16+l15)
    Fw[l15] = lsum;
    const f32x4 lv = *(const f32x4*)&Fw[l4 * 4];
#pragma unroll
    for (int dc = 0; dc < 4; ++dc) {
      const int col = h * DKc + dc * 16 + l15;
#pragma unroll
      for (int r = 0; r < 4; ++r)
        O[(size_t)(b * Sc + q0 + l4 * 4 + r) * DMc + col] = f2b(o[dc][r] / lv[r]);
    }
  }
}

// ---------------- launch ------------------------------------------------------
extern "C" void kernel_launch(void* const* d_in, const int* in_sizes, int n_in,
                              void* d_out, int out_size, void* d_ws, size_t ws_size,
                              hipStream_t stream)
{
  const float* x      = (const float*)d_in[0];
  const int*   tokpos = (const int*)d_in[1];
  const float* qkv_w  = (const float*)d_in[2];
  const float* out_w  = (const float*)d_in[3];
  float* out = (float*)d_out;

  char* ws = (char*)d_ws;
  size_t off = 0;
  u16* xb   = (u16*)(ws + off); off += (size_t)Mc * DMc * 2;
  u16* qwb  = (u16*)(ws + off); off += (size_t)3 * DMc * DMc * 2;
  u16* owb  = (u16*)(ws + off); off += (size_t)DMc * DMc * 2;
  u16* qkv  = (u16*)(ws + off); off += (size_t)Mc * 3 * DMc * 2;
  u16* Qr   = (u16*)(ws + off); off += (size_t)Bc * Hc * Sc * DKc * 2;
  u16* Kr   = (u16*)(ws + off); off += (size_t)Bc * Hc * Sc * DKc * 2;
  u16* Vt   = (u16*)(ws + off); off += (size_t)Bc * Hc * DKc * Sc * 2;
  u16* Oa   = (u16*)(ws + off); off += (size_t)Mc * DMc * 2;
  float2* tab = (float2*)(ws + off); off += (size_t)Sc * 32 * sizeof(float2);

  cvt_f32_bf16_k<<<(Mc * DMc / 8 + 255) / 256, 256, 0, stream>>>(x, xb, Mc * DMc / 8);
  cvt_f32_bf16_k<<<(3 * DMc * DMc / 8 + 255) / 256, 256, 0, stream>>>(qkv_w, qwb, 3 * DMc * DMc / 8);
  cvt_f32_bf16_k<<<(DMc * DMc / 8 + 255) / 256, 256, 0, stream>>>(out_w, owb, DMc * DMc / 8);

  rope_table_k<<<(Sc * 32) / 256, 256, 0, stream>>>(tab);
  gemm_bt128<u16><<<dim3(Mc / 128, 3 * DMc / 128), 256, 0, stream>>>(xb, qwb, qkv, Mc, 3 * DMc, DMc);
  rope_reshape_k<<<dim3(Sc / 64, Hc, Bc), 256, 0, stream>>>(qkv, tokpos, tab, Qr, Kr, Vt);
  attn_k<<<dim3(16, Hc, Bc), 256, 0, stream>>>(Qr, Kr, Vt, Oa);
  gemm_bt128<float><<<dim3(Mc / 128, DMc / 128), 256, 0, stream>>>(Oa, owb, out, Mc, DMc, DMc);
}

// Round 6
// 133.787 us; speedup vs baseline: 3.0768x; 1.5551x over previous
//
#include <hip/hip_runtime.h>
#include <cstdint>

typedef unsigned short u16;
typedef unsigned int u32;
typedef __attribute__((ext_vector_type(8))) short short8;
typedef __attribute__((ext_vector_type(4))) float f32x4;

static constexpr int Bc = 2, Sc = 2048, DMc = 1024, Hc = 16, DKc = 64;
static constexpr int Mc = Bc * Sc; // 4096

__device__ __forceinline__ float b2f(u16 u) { return __uint_as_float((u32)u << 16); }
__device__ __forceinline__ u16 f2b(float f) {
  u32 x = __float_as_uint(f);
  return (u16)((x + 0x7fffu + ((x >> 16) & 1u)) >> 16);
}
__device__ __forceinline__ u32 pack2(float lo, float hi) {
  return (u32)f2b(lo) | ((u32)f2b(hi) << 16);
}

// ---------------- f32 -> bf16 conversion (RTNE), 8 elems/thread ---------------
__global__ __launch_bounds__(256)
void cvt_f32_bf16_k(const float* __restrict__ src, u16* __restrict__ dst, int n8)
{
  const int i = blockIdx.x * 256 + threadIdx.x;
  if (i >= n8) return;
  const float4 a = *(const float4*)(src + (size_t)i * 8);
  const float4 b = *(const float4*)(src + (size_t)i * 8 + 4);
  uint4 o;
  o.x = pack2(a.x, a.y);
  o.y = pack2(a.z, a.w);
  o.z = pack2(b.x, b.y);
  o.w = pack2(b.z, b.w);
  *(uint4*)(dst + (size_t)i * 8) = o;
}

// ---------------- GEMM: C[M][N] = A[M][K] * W[N][K]^T, bf16 in, f32 acc -------
template <typename OutT>
__global__ __launch_bounds__(256, 2)
void gemm_bt128(const u16* __restrict__ A, const u16* __restrict__ W,
                OutT* __restrict__ C, int M, int N, int K)
{
  __shared__ u16 As[128 * 32];
  __shared__ u16 Bs[128 * 32];
  const int t = threadIdx.x;
  const int w = t >> 6, l = t & 63;
  const int wr = w >> 1, wc = w & 1;
  const int l4 = l >> 4, l15 = l & 15;
  const int bm = blockIdx.x, bn = blockIdx.y;

  f32x4 acc[4][4] = {};

  const int rowA = bm * 128, rowB = bn * 128;
  const int sr = l >> 2, sk = (l & 3) * 8;

  for (int k0 = 0; k0 < K; k0 += 32) {
    __syncthreads();
#pragma unroll
    for (int i = 0; i < 2; ++i) {
      const int chunk = i * 4 + w;
      const u16* ga = A + (size_t)(rowA + chunk * 16 + sr) * K + k0 + sk;
      const u16* gb = W + (size_t)(rowB + chunk * 16 + sr) * K + k0 + sk;
      __builtin_amdgcn_global_load_lds((const __attribute__((address_space(1))) void*)ga,
                                       (__attribute__((address_space(3))) void*)(As + chunk * 512), 16, 0, 0);
      __builtin_amdgcn_global_load_lds((const __attribute__((address_space(1))) void*)gb,
                                       (__attribute__((address_space(3))) void*)(Bs + chunk * 512), 16, 0, 0);
    }
    __syncthreads();
    short8 af[4], bf[4];
#pragma unroll
    for (int m = 0; m < 4; ++m)
      af[m] = *(const short8*)(As + (wr * 64 + m * 16 + l15) * 32 + l4 * 8);
#pragma unroll
    for (int n = 0; n < 4; ++n)
      bf[n] = *(const short8*)(Bs + (wc * 64 + n * 16 + l15) * 32 + l4 * 8);
#pragma unroll
    for (int m = 0; m < 4; ++m)
#pragma unroll
      for (int n = 0; n < 4; ++n)
        acc[m][n] = __builtin_amdgcn_mfma_f32_16x16x32_bf16(af[m], bf[n], acc[m][n], 0, 0, 0);
  }

#pragma unroll
  for (int m = 0; m < 4; ++m) {
    const int r0 = rowA + wr * 64 + m * 16 + l4 * 4;
#pragma unroll
    for (int n = 0; n < 4; ++n) {
      const int c0 = rowB + wc * 64 + n * 16 + l15;
#pragma unroll
      for (int r = 0; r < 4; ++r) {
        const float v = acc[m][n][r];
        if constexpr (sizeof(OutT) == 2)
          C[(size_t)(r0 + r) * N + c0] = (OutT)f2b(v);
        else
          C[(size_t)(r0 + r) * N + c0] = (OutT)v;
      }
    }
  }
}

// ---------------- RoPE cos/sin table: [S][32] float2 --------------------------
__global__ void rope_table_k(float2* __restrict__ tab)
{
  const int idx = blockIdx.x * 256 + threadIdx.x;
  const int p = idx >> 5, i = idx & 31;
  const float invf = powf(10000.0f, -(float)(2 * i) / 64.0f);
  const float ang = (float)p * invf;
  tab[idx] = make_float2(cosf(ang), sinf(ang));
}

// ---------------- RoPE apply + relayout ---------------------------------------
__global__ __launch_bounds__(256)
void rope_reshape_k(const u16* __restrict__ qkv, const int* __restrict__ tokpos,
                    const float2* __restrict__ tab,
                    u16* __restrict__ Q, u16* __restrict__ K, u16* __restrict__ Vt)
{
  __shared__ u16 Vs[64][72];
  const int t = threadIdx.x;
  const int st = blockIdx.x, h = blockIdx.y, b = blockIdx.z;

  {
    const int sl = t >> 2, iq = t & 3;
    const int s = st * 64 + sl;
    const int p = tokpos[b * Sc + s];
    const size_t row = (size_t)(b * Sc + s) * 3 * DMc + h * DKc + iq * 16;
    const size_t orow = ((size_t)(b * Hc + h) * Sc + s) * DKc + iq * 16;
#pragma unroll
    for (int which = 0; which < 2; ++which) {
      const u16* g = qkv + row + which * DMc;
      uint4 va = *(const uint4*)g;
      uint4 vb = *(const uint4*)(g + 8);
      u32 in[8] = {va.x, va.y, va.z, va.w, vb.x, vb.y, vb.z, vb.w};
      const float scale = (which == 0) ? 0.125f : 1.0f;
      u32 ow[8];
#pragma unroll
      for (int j = 0; j < 8; ++j) {
        const float2 cs = tab[p * 32 + iq * 8 + j];
        const float t1 = b2f((u16)(in[j] & 0xffffu));
        const float t2 = b2f((u16)(in[j] >> 16));
        ow[j] = pack2((t1 * cs.x - t2 * cs.y) * scale, (t1 * cs.y + t2 * cs.x) * scale);
      }
      u16* dst = (which == 0 ? Q : K) + orow;
      *(uint4*)dst = make_uint4(ow[0], ow[1], ow[2], ow[3]);
      *(uint4*)(dst + 8) = make_uint4(ow[4], ow[5], ow[6], ow[7]);
    }
  }
#pragma unroll
  for (int it = 0; it < 2; ++it) {
    const int sv = it * 32 + (t >> 3);
    const int d0 = (t & 7) * 8;
    const u16* g = qkv + (size_t)(b * Sc + st * 64 + sv) * 3 * DMc + 2 * DMc + h * DKc + d0;
    *(uint4*)&Vs[sv][d0] = *(const uint4*)g;
  }
  __syncthreads();
  {
    const int d = t >> 2, s0 = (t & 3) * 16;
    u16 tmp[16];
#pragma unroll
    for (int j = 0; j < 16; ++j) tmp[j] = Vs[s0 + j][d];
    u16* dst = Vt + ((size_t)(b * Hc + h) * DKc + d) * Sc + st * 64 + s0;
    *(uint4*)dst = *(const uint4*)tmp;
    *(uint4*)(dst + 8) = *(const uint4*)(tmp + 8);
  }
}

// ---------------- causal flash attention --------------------------------------
// Swapped-QK^T + block-cooperative double-buffered LDS staging of K/V.
// grid (16,H,B)=512 blocks x 4 waves; wave = 16-row strip, tile pair (31-p,p)
// -> 33 KBLK=64 iters per wave, identical across ALL waves (barriers legal).
// K/V staged once per block per tile via global_load_lds (4x traffic cut);
// raw s_barrier + counted vmcnt(4) keeps next tile's loads in flight (no
// __syncthreads: its vmcnt(0) drain would serialize the prefetch).
// XOR swizzle (pre-swizzled global src + swizzled ds_read) for conflict-free
// 128B-stride reads.  XCD remap: 4 (b,h) per XCD L2.
__global__ __launch_bounds__(256, 2)
void attn_k(const u16* __restrict__ Q, const u16* __restrict__ K,
            const u16* __restrict__ Vt, u16* __restrict__ O)
{
  __shared__ u16 Kls[2][64 * 64];  // [buf][kv 64][d 64], rows XOR-swizzled
  __shared__ u16 Vls[2][64 * 64];  // [buf][d 64][kv 64], rows XOR-swizzled
  __shared__ u16 Psh[4][16 * 64];  // per-wave P tile, XOR-swizzled
  __shared__ float Fsh[4][16];     // per-wave lane->reg redistribution

  const int t = threadIdx.x, w = t >> 6, l = t & 63;
  const int l4 = l >> 4, l15 = l & 15;

  int bid = blockIdx.x + 16 * (blockIdx.y + Hc * blockIdx.z);
  bid = (bid & 7) * 64 + (bid >> 3); // XCD-contiguous remap (bijective)
  const int p = bid & 15, h = (bid >> 4) & 15, b = bid >> 8;

  const size_t bh = (size_t)b * Hc + h;
  const u16* Qb = Q + bh * Sc * DKc;
  const u16* Kb = K + bh * Sc * DKc;
  const u16* Vb = Vt + bh * (size_t)DKc * Sc;
  char* Pw = (char*)&Psh[w][0];
  float* Fw = &Fsh[w][0];
  const int swz = (l15 & 7) << 4;

  // staging geometry: entry e = j*256+t covers LDS bytes e*16..e*16+15
  // (row = e>>3, linear col-byte (e&7)*16); global source col pre-swizzled.
  int srow[2], scol[2];
#pragma unroll
  for (int j = 0; j < 2; ++j) {
    const int e = j * 256 + t;
    srow[j] = e >> 3;
    scol[j] = (((e & 7) * 16) ^ ((srow[j] & 7) << 4)) >> 1;
  }

  auto stage = [&](int buf, int kv0) {
#pragma unroll
    for (int j = 0; j < 2; ++j) {
      const u16* gk = Kb + (size_t)(kv0 + srow[j]) * DKc + scol[j];
      __builtin_amdgcn_global_load_lds((const __attribute__((address_space(1))) void*)gk,
          (__attribute__((address_space(3))) void*)(&Kls[buf][0] + (j * 256 + w * 64) * 8), 16, 0, 0);
    }
#pragma unroll
    for (int j = 0; j < 2; ++j) {
      const u16* gv = Vb + (size_t)srow[j] * Sc + kv0 + scol[j];
      __builtin_amdgcn_global_load_lds((const __attribute__((address_space(1))) void*)gv,
          (__attribute__((address_space(3))) void*)(&Vls[buf][0] + (j * 256 + w * 64) * 8), 16, 0, 0);
    }
  };

#pragma unroll
  for (int seg = 0; seg < 2; ++seg) {
    const int qt = seg ? p : 31 - p;
    const int q0 = qt * 64 + w * 16;
    const int niter = qt + 1;

    // Q B-frags: row(q)=l15, k(d)=8*l4+j
    const short8 qf0 = *(const short8*)(Qb + (size_t)(q0 + l15) * DKc + l4 * 8);
    const short8 qf1 = *(const short8*)(Qb + (size_t)(q0 + l15) * DKc + 32 + l4 * 8);

    f32x4 o[4] = {};
    float m = -1e30f, lsum = 0.f;

    stage(0, 0); // prologue
    for (int it = 0; it < niter; ++it) {
      const int buf = it & 1;
      const int kv0 = it * 64;
      if (it + 1 < niter) {
        stage(buf ^ 1, kv0 + 64);
        asm volatile("s_waitcnt vmcnt(4)" ::: "memory"); // current buf landed
      } else {
        asm volatile("s_waitcnt vmcnt(0)" ::: "memory");
      }
      __builtin_amdgcn_s_barrier(); // all waves' stages landed

      const char* Kbuf = (const char*)&Kls[buf][0];
      const char* Vbuf = (const char*)&Vls[buf][0];

      // S^T subtiles: kv = kv0 + c*16 + l4*4 + r, q = q0 + l15
      f32x4 sc[4];
#pragma unroll
      for (int c = 0; c < 4; ++c) {
        const int rb = (c * 16 + l15) * 128;
        const short8 ka  = *(const short8*)(Kbuf + rb + ((l4 * 16) ^ swz));
        const short8 kb2 = *(const short8*)(Kbuf + rb + ((64 + l4 * 16) ^ swz));
        f32x4 z = {0.f, 0.f, 0.f, 0.f};
        z = __builtin_amdgcn_mfma_f32_16x16x32_bf16(ka, qf0, z, 0, 0, 0);
        z = __builtin_amdgcn_mfma_f32_16x16x32_bf16(kb2, qf1, z, 0, 0, 0);
        sc[c] = z;
      }
      if (kv0 + 63 > q0) { // causal mask (wave-uniform trigger)
#pragma unroll
        for (int c = 0; c < 4; ++c) {
          const int kvr = kv0 + c * 16 + l4 * 4;
#pragma unroll
          for (int r = 0; r < 4; ++r)
            if (kvr + r > q0 + l15) sc[c][r] = -1e30f;
        }
      }
      // online softmax: in-lane + 2 shfl
      float pmax = -1e30f;
#pragma unroll
      for (int c = 0; c < 4; ++c)
        pmax = fmaxf(pmax, fmaxf(fmaxf(sc[c][0], sc[c][1]), fmaxf(sc[c][2], sc[c][3])));
      pmax = fmaxf(pmax, __shfl_xor(pmax, 16));
      pmax = fmaxf(pmax, __shfl_xor(pmax, 32));
      const float mnew = fmaxf(m, pmax);
      const float fac = __expf(m - mnew);
      float rs = 0.f;
#pragma unroll
      for (int c = 0; c < 4; ++c) {
        const float p0 = __expf(sc[c][0] - mnew);
        const float p1 = __expf(sc[c][1] - mnew);
        const float p2 = __expf(sc[c][2] - mnew);
        const float p3 = __expf(sc[c][3] - mnew);
        rs += (p0 + p1) + (p2 + p3);
        uint2 pk;
        pk.x = pack2(p0, p1);
        pk.y = pack2(p2, p3);
        *(uint2*)(Pw + ((l15 * 128 + c * 32 + l4 * 8) ^ swz)) = pk; // P[q][kv]
      }
      rs += __shfl_xor(rs, 16);
      rs += __shfl_xor(rs, 32);
      lsum = lsum * fac + rs;
      m = mnew;
      // fac: lane-domain (q=l15) -> reg-domain (q=l4*4+r)
      Fw[l15] = fac;
      const f32x4 f4 = *(const f32x4*)&Fw[l4 * 4];
#pragma unroll
      for (int dc = 0; dc < 4; ++dc) {
        o[dc][0] *= f4[0]; o[dc][1] *= f4[1];
        o[dc][2] *= f4[2]; o[dc][3] *= f4[3];
      }
      // PV: A = P rows (q=l15, kv=kv2*32+8*l4+j), B = V rows from LDS
#pragma unroll
      for (int kv2 = 0; kv2 < 2; ++kv2) {
        const short8 pa = *(const short8*)(Pw + ((l15 * 128 + kv2 * 64 + l4 * 16) ^ swz));
#pragma unroll
        for (int dc = 0; dc < 4; ++dc) {
          const short8 vf = *(const short8*)(Vbuf + (dc * 16 + l15) * 128 + ((kv2 * 64 + l4 * 16) ^ swz));
          o[dc] = __builtin_amdgcn_mfma_f32_16x16x32_bf16(pa, vf, o[dc], 0, 0, 0);
        }
      }
      asm volatile("s_waitcnt lgkmcnt(0)" ::: "memory");
      __builtin_amdgcn_s_barrier(); // all waves done reading buf
    }
    // epilogue: lsum lane->reg, normalize, store
    Fw[l15] = lsum;
    const f32x4 lv = *(const f32x4*)&Fw[l4 * 4];
#pragma unroll
    for (int dc = 0; dc < 4; ++dc) {
      const int col = h * DKc + dc * 16 + l15;
#pragma unroll
      for (int r = 0; r < 4; ++r)
        O[(size_t)(b * Sc + q0 + l4 * 4 + r) * DMc + col] = f2b(o[dc][r] / lv[r]);
    }
  }
}

// ---------------- launch ------------------------------------------------------
extern "C" void kernel_launch(void* const* d_in, const int* in_sizes, int n_in,
                              void* d_out, int out_size, void* d_ws, size_t ws_size,
                              hipStream_t stream)
{
  const float* x      = (const float*)d_in[0];
  const int*   tokpos = (const int*)d_in[1];
  const float* qkv_w  = (const float*)d_in[2];
  const float* out_w  = (const float*)d_in[3];
  float* out = (float*)d_out;

  char* ws = (char*)d_ws;
  size_t off = 0;
  u16* xb   = (u16*)(ws + off); off += (size_t)Mc * DMc * 2;
  u16* qwb  = (u16*)(ws + off); off += (size_t)3 * DMc * DMc * 2;
  u16* owb  = (u16*)(ws + off); off += (size_t)DMc * DMc * 2;
  u16* qkv  = (u16*)(ws + off); off += (size_t)Mc * 3 * DMc * 2;
  u16* Qr   = (u16*)(ws + off); off += (size_t)Bc * Hc * Sc * DKc * 2;
  u16* Kr   = (u16*)(ws + off); off += (size_t)Bc * Hc * Sc * DKc * 2;
  u16* Vt   = (u16*)(ws + off); off += (size_t)Bc * Hc * DKc * Sc * 2;
  u16* Oa   = (u16*)(ws + off); off += (size_t)Mc * DMc * 2;
  float2* tab = (float2*)(ws + off); off += (size_t)Sc * 32 * sizeof(float2);

  cvt_f32_bf16_k<<<(Mc * DMc / 8 + 255) / 256, 256, 0, stream>>>(x, xb, Mc * DMc / 8);
  cvt_f32_bf16_k<<<(3 * DMc * DMc / 8 + 255) / 256, 256, 0, stream>>>(qkv_w, qwb, 3 * DMc * DMc / 8);
  cvt_f32_bf16_k<<<(DMc * DMc / 8 + 255) / 256, 256, 0, stream>>>(out_w, owb, DMc * DMc / 8);

  rope_table_k<<<(Sc * 32) / 256, 256, 0, stream>>>(tab);
  gemm_bt128<u16><<<dim3(Mc / 128, 3 * DMc / 128), 256, 0, stream>>>(xb, qwb, qkv, Mc, 3 * DMc, DMc);
  rope_reshape_k<<<dim3(Sc / 64, Hc, Bc), 256, 0, stream>>>(qkv, tokpos, tab, Qr, Kr, Vt);
  attn_k<<<dim3(16, Hc, Bc), 256, 0, stream>>>(Qr, Kr, Vt, Oa);
  gemm_bt128<float><<<dim3(Mc / 128, DMc / 128), 256, 0, stream>>>(Oa, owb, out, Mc, DMc, DMc);
}